// Round 1
// 931.905 us; speedup vs baseline: 1.1931x; 1.1931x over previous
//
#include <hip/hip_runtime.h>
#include <hip/hip_bf16.h>
#include <stdint.h>

#define T_SEQ 2048
#define HID   4096
#define NQKV  12288
#define NH    32
#define HD    128

typedef __attribute__((ext_vector_type(8))) short bf16x8;
typedef __attribute__((ext_vector_type(4))) float f32x4;

__device__ __forceinline__ unsigned short f2b(float f) {
    __hip_bfloat16 h = __float2bfloat16(f);
    return *reinterpret_cast<unsigned short*>(&h);
}
__device__ __forceinline__ unsigned int pack2(float a, float b) {
    return (unsigned int)f2b(a) | ((unsigned int)f2b(b) << 16);
}
__device__ __forceinline__ f32x4 mfma16(bf16x8 a, bf16x8 b, f32x4 c) {
    return __builtin_amdgcn_mfma_f32_16x16x32_bf16(a, b, c, 0, 0, 0);
}
__device__ __forceinline__ void gld_lds16(const void* g, void* l) {
    __builtin_amdgcn_global_load_lds(
        (const __attribute__((address_space(1))) unsigned int*)g,
        (__attribute__((address_space(3))) unsigned int*)l, 16, 0, 0);
}

// ---------------- cast fp32 -> bf16, 4 elems/thread ----------------
__global__ __launch_bounds__(256) void cast_f32_bf16(const float* __restrict__ src,
                                                     unsigned short* __restrict__ dst) {
    int i = (blockIdx.x * 256 + threadIdx.x) * 4;
    float4 v = *(const float4*)(src + i);
    ushort4 o;
    o.x = f2b(v.x); o.y = f2b(v.y); o.z = f2b(v.z); o.w = f2b(v.w);
    *(ushort4*)(dst + i) = o;
}

// ---------------- transpose: src fp32 [R][C] -> dst bf16 [C][R] ----------------
__global__ __launch_bounds__(256) void transpose_f32_bf16(const float* __restrict__ src,
                                                          unsigned short* __restrict__ dst,
                                                          int R, int C) {
    __shared__ float tile[64][65];
    int r0 = blockIdx.x * 64, c0 = blockIdx.y * 64;
    int tid = threadIdx.x;
#pragma unroll
    for (int i = 0; i < 4; i++) {
        int e = (tid + 256 * i) * 4;
        int r = e >> 6, c = e & 63;
        float4 v = *(const float4*)(src + (size_t)(r0 + r) * C + c0 + c);
        tile[r][c + 0] = v.x; tile[r][c + 1] = v.y;
        tile[r][c + 2] = v.z; tile[r][c + 3] = v.w;
    }
    __syncthreads();
#pragma unroll
    for (int i = 0; i < 4; i++) {
        int e = (tid + 256 * i) * 4;
        int rr = e >> 6, cc = e & 63;  // rr: dst row (= src col), cc: dst col (= src row)
        ushort4 o;
        o.x = f2b(tile[cc + 0][rr]); o.y = f2b(tile[cc + 1][rr]);
        o.z = f2b(tile[cc + 2][rr]); o.w = f2b(tile[cc + 3][rr]);
        *(ushort4*)(dst + (size_t)(c0 + rr) * R + r0 + cc) = o;
    }
}

// ---------------- GEMM: C[M][N] = A[M][K] @ Bt[N][K]^T (+bias), fp32 out ----------------
// 128x128 tile, BK=32, 4 waves, each wave 64x64 (4x4 16x16x32 MFMA frags)
template <int WITH_BIAS>
__global__ __launch_bounds__(256) void gemm_bt(const unsigned short* __restrict__ A,
                                               const unsigned short* __restrict__ Bt,
                                               const float* __restrict__ bias,
                                               float* __restrict__ C,
                                               int N, int K) {
    __shared__ __align__(16) unsigned short As[128 * 32];
    __shared__ __align__(16) unsigned short Bs[128 * 32];
    int tid = threadIdx.x;
    int w = tid >> 6, lane = tid & 63;
    int quad = lane >> 4, cl = lane & 15;
    int wm = w >> 1, wn = w & 1;
    const unsigned short* Ablk = A + (size_t)blockIdx.x * 128 * K;
    const unsigned short* Bblk = Bt + (size_t)blockIdx.y * 128 * K;
    int srow = lane >> 2, scol = (lane & 3) * 8;
    f32x4 acc[4][4] = {};
    for (int k0 = 0; k0 < K; k0 += 32) {
#pragma unroll
        for (int u = 0; u < 2; u++) {
            int cidx = 2 * w + u;  // wave-uniform chunk id; 8 chunks of 16 rows
            gld_lds16(Ablk + (size_t)(cidx * 16 + srow) * K + k0 + scol, &As[cidx * 512]);
            gld_lds16(Bblk + (size_t)(cidx * 16 + srow) * K + k0 + scol, &Bs[cidx * 512]);
        }
        __syncthreads();
        bf16x8 af[4], bfr[4];
#pragma unroll
        for (int i = 0; i < 4; i++)
            af[i] = *(const bf16x8*)&As[(wm * 64 + i * 16 + cl) * 32 + quad * 8];
#pragma unroll
        for (int j = 0; j < 4; j++)
            bfr[j] = *(const bf16x8*)&Bs[(wn * 64 + j * 16 + cl) * 32 + quad * 8];
#pragma unroll
        for (int i = 0; i < 4; i++)
#pragma unroll
            for (int j = 0; j < 4; j++)
                acc[i][j] = mfma16(af[i], bfr[j], acc[i][j]);
        __syncthreads();
    }
#pragma unroll
    for (int i = 0; i < 4; i++) {
        int row0 = blockIdx.x * 128 + wm * 64 + i * 16 + quad * 4;
#pragma unroll
        for (int j = 0; j < 4; j++) {
            int col = blockIdx.y * 128 + wn * 64 + j * 16 + cl;
            float bv = WITH_BIAS ? bias[col] : 0.f;
#pragma unroll
            for (int r = 0; r < 4; r++)
                C[(size_t)(row0 + r) * N + col] = acc[i][j][r] + bv;
        }
    }
}

// ---------------- RMSNorm (full 4096-dim) + RoPE -> bf16 q,k ----------------
__global__ __launch_bounds__(256) void rmsnorm_rope(const float* __restrict__ qkv,
                                                    const float* __restrict__ qw,
                                                    const float* __restrict__ kw,
                                                    unsigned short* __restrict__ qo,
                                                    unsigned short* __restrict__ ko) {
    int t = blockIdx.x, tid = threadIdx.x;
    const float* row = qkv + (size_t)t * NQKV;
    float sq = 0.f, sk = 0.f;
    for (int i = tid; i < HID; i += 256) {
        float x = row[i];        sq += x * x;
        float y = row[HID + i];  sk += y * y;
    }
#pragma unroll
    for (int off = 32; off > 0; off >>= 1) {
        sq += __shfl_xor(sq, off, 64);
        sk += __shfl_xor(sk, off, 64);
    }
    __shared__ float red[2][4];
    if ((tid & 63) == 0) { red[0][tid >> 6] = sq; red[1][tid >> 6] = sk; }
    __syncthreads();
    sq = red[0][0] + red[0][1] + red[0][2] + red[0][3];
    sk = red[1][0] + red[1][1] + red[1][2] + red[1][3];
    float rq = rsqrtf(sq * (1.0f / HID) + 1e-6f);
    float rk = rsqrtf(sk * (1.0f / HID) + 1e-6f);
    for (int p = tid; p < 2048; p += 256) {
        int h = p >> 6, d = p & 63;
        int c1 = h * 128 + d, c2 = c1 + 64;
        // inv_freq = theta^(-d/64), ln(1e6)/64 = 0.2158673524681918
        float inv = expf(-(float)d * 0.2158673524681918f);
        float ang = (float)t * inv;
        float sn, cs;
        sincosf(ang, &sn, &cs);
        float x1 = row[c1] * rq * qw[c1];
        float x2 = row[c2] * rq * qw[c2];
        qo[(size_t)t * HID + c1] = f2b(x1 * cs - x2 * sn);
        qo[(size_t)t * HID + c2] = f2b(x2 * cs + x1 * sn);
        float y1 = row[HID + c1] * rk * kw[c1];
        float y2 = row[HID + c2] * rk * kw[c2];
        ko[(size_t)t * HID + c1] = f2b(y1 * cs - y2 * sn);
        ko[(size_t)t * HID + c2] = f2b(y2 * cs + y1 * sn);
    }
}

// ---------------- V transpose: qkv fp32 v-part -> vT[NH][128][T] bf16 ----------------
__global__ __launch_bounds__(256) void v_transpose(const float* __restrict__ qkv,
                                                   unsigned short* __restrict__ vT) {
    __shared__ float tile[64][129];
    int t0 = blockIdx.x * 64, h = blockIdx.y, tid = threadIdx.x;
#pragma unroll 4
    for (int i = 0; i < 32; i++) {
        int e = tid + 256 * i;
        int r = e >> 7, d = e & 127;
        tile[r][d] = qkv[(size_t)(t0 + r) * NQKV + 2 * HID + h * 128 + d];
    }
    __syncthreads();
#pragma unroll 4
    for (int i = 0; i < 32; i++) {
        int e = tid + 256 * i;
        int d = e >> 6, r = e & 63;
        vT[(size_t)h * (128 * T_SEQ) + (size_t)d * T_SEQ + t0 + r] = f2b(tile[r][d]);
    }
}

// ---------------- flash attention v2 ----------------
// Block = 4 waves x 32 q-rows = 128 q rows of one head. No K-split, no combine.
// K tile (32x128) and V^T tile (128x32) double-buffered in LDS via global_load_lds,
// 16B chunks XOR-swizzled on the GLOBAL source (LDS dest stays lane-linear) so the
// ds_read_b128 fragment reads are at the wave64-b128 bank floor (conflict-free).
// Pipeline: stage(t+1) -> compute(t) -> __syncthreads (drains vmcnt) per tile.
__global__ __launch_bounds__(256) void attn_kernel(const unsigned short* __restrict__ Q,
                                                   const unsigned short* __restrict__ Kb,
                                                   const unsigned short* __restrict__ Vt,
                                                   unsigned short* __restrict__ O) {
    __shared__ __align__(16) unsigned short Ktile[2][4096];  // [buf][32 keys][128 d] swizzled
    __shared__ __align__(16) unsigned short Vtile[2][4096];  // [buf][128 d][32 keys] swizzled

    int w = threadIdx.x >> 6, lane = threadIdx.x & 63;
    int quad = lane >> 4, cl = lane & 15;
    int h = blockIdx.x;
    int y = blockIdx.y;
    // heavy strips dispatched first; pair (15-y, y-8) so co-resident blocks sum equal work
    int strip = (y < 8) ? (15 - y) : (y - 8);
    int qbase = strip * 128;
    int qw0 = qbase + w * 32;   // this wave's first q row
    int qmaxw = qw0 + 31;       // causal limit of this wave
    const float scale = 0.08838834764831845f;  // 1/sqrt(128)

    const unsigned short* Kh = Kb + h * 128;
    const unsigned short* vh = Vt + (size_t)h * (128 * T_SEQ);

    // Q fragments (B-frag): bq[qh][s] rows = q, contiguous d
    bf16x8 bq[2][4];
#pragma unroll
    for (int qh = 0; qh < 2; qh++)
#pragma unroll
        for (int s = 0; s < 4; s++)
            bq[qh][s] = *(const bf16x8*)&Q[(size_t)(qw0 + qh * 16 + cl) * HID + h * 128 + s * 32 + quad * 8];

    f32x4 o[2][8] = {};                       // [qh][dc] accumulators (64 VGPR)
    float m_run[2] = {-1e30f, -1e30f};
    float l_run[2] = {0.f, 0.f};

    int ntiles = strip * 4 + 4;

    // K chunk p in [0,512): row=p>>4, LDS slot p&15 holds global 16B chunk (p&15)^(row&7)
    // V chunk p in [0,512): d=p>>2,  LDS slot p&3  holds global 16B chunk (p&3)^(d&3)
#define STAGE(b, kt2) do {                                                       \
        int kb2 = (kt2) * 32;                                                    \
        if (w < 2) {                                                             \
            _Pragma("unroll")                                                    \
            for (int i = 0; i < 4; i++) {                                        \
                int p = w * 256 + i * 64 + lane;                                 \
                int row = p >> 4;                                                \
                int c = (p & 15) ^ (row & 7);                                    \
                gld_lds16(Kh + (size_t)(kb2 + row) * HID + c * 8,                \
                          &Ktile[b][(w * 256 + i * 64) * 8]);                    \
            }                                                                    \
        } else {                                                                 \
            _Pragma("unroll")                                                    \
            for (int i = 0; i < 4; i++) {                                        \
                int p = (w - 2) * 256 + i * 64 + lane;                           \
                int d = p >> 2;                                                  \
                int c = (p & 3) ^ (d & 3);                                       \
                gld_lds16(vh + (size_t)d * T_SEQ + kb2 + c * 8,                  \
                          &Vtile[b][((w - 2) * 256 + i * 64) * 8]);              \
            }                                                                    \
        }                                                                        \
    } while (0)

    STAGE(0, 0);
    __syncthreads();

    int buf = 0;
    for (int kt = 0; kt < ntiles; kt++) {
        if (kt + 1 < ntiles) STAGE(buf ^ 1, kt + 1);   // prefetch overlaps compute
        int kb = kt * 32;
        if (kb <= qmaxw) {                              // wave-uniform causal skip
            const unsigned short* Kl = Ktile[buf];
            const unsigned short* Vl = Vtile[buf];
            // ---- QK^T: S^T[key][q], A = K rows, B = Q cols ----
            f32x4 sA[2][2] = {};   // [qh][kh]
#pragma unroll
            for (int s = 0; s < 4; s++) {
                int swz = (((s * 4 + quad) ^ (cl & 7)) * 8);
                bf16x8 ak0 = *(const bf16x8*)&Kl[cl * 128 + swz];
                bf16x8 ak1 = *(const bf16x8*)&Kl[(16 + cl) * 128 + swz];
                sA[0][0] = mfma16(ak0, bq[0][s], sA[0][0]);
                sA[0][1] = mfma16(ak1, bq[0][s], sA[0][1]);
                sA[1][0] = mfma16(ak0, bq[1][s], sA[1][0]);
                sA[1][1] = mfma16(ak1, bq[1][s], sA[1][1]);
            }
            bf16x8 ap[2];
#pragma unroll
            for (int qh = 0; qh < 2; qh++) {
                int qrow = qw0 + qh * 16 + cl;          // softmax state lives at q = cl
                float p0[4], p1[4];
                float tm = -1e30f;
#pragma unroll
                for (int r = 0; r < 4; r++) {
                    int k0i = kb + quad * 4 + r;
                    float v0 = (k0i      <= qrow) ? sA[qh][0][r] * scale : -1e30f;
                    float v1 = (k0i + 16 <= qrow) ? sA[qh][1][r] * scale : -1e30f;
                    p0[r] = v0; p1[r] = v1;
                    tm = fmaxf(tm, fmaxf(v0, v1));
                }
                tm = fmaxf(tm, __shfl_xor(tm, 16, 64));
                tm = fmaxf(tm, __shfl_xor(tm, 32, 64));
                float m_new = fmaxf(m_run[qh], tm);
                float alpha = __expf(m_run[qh] - m_new);
                float ps = 0.f;
#pragma unroll
                for (int r = 0; r < 4; r++) {
                    p0[r] = __expf(p0[r] - m_new);
                    p1[r] = __expf(p1[r] - m_new);
                    ps += p0[r] + p1[r];
                }
                ps += __shfl_xor(ps, 16, 64);
                ps += __shfl_xor(ps, 32, 64);
                l_run[qh] = l_run[qh] * alpha + ps;
                m_run[qh] = m_new;
                // o rows are q = quad*4+r -> broadcast those rows' alpha
                float ar[4];
#pragma unroll
                for (int r = 0; r < 4; r++)
                    ar[r] = __shfl(alpha, quad * 4 + r, 64);
#pragma unroll
                for (int dc = 0; dc < 8; dc++) {
                    o[qh][dc][0] *= ar[0]; o[qh][dc][1] *= ar[1];
                    o[qh][dc][2] *= ar[2]; o[qh][dc][3] *= ar[3];
                }
                // P: S^T C-layout (key=quad*4+r, qcol=cl) -> A-layout (m=cl, key=quad*8+j)
                unsigned int ph0[2], ph1[2];
                ph0[0] = pack2(p0[0], p0[1]); ph0[1] = pack2(p0[2], p0[3]);
                ph1[0] = pack2(p1[0], p1[1]); ph1[1] = pack2(p1[2], p1[3]);
                union { unsigned int u[4]; bf16x8 v; } apv;
#pragma unroll
                for (int i = 0; i < 4; i++) {
                    int tloc = (4 * quad + i) & 7;
                    int srcLane = ((tloc >> 1) << 4) | cl;
                    unsigned int u0 = (unsigned int)__shfl((int)ph0[i & 1], srcLane, 64);
                    unsigned int u1 = (unsigned int)__shfl((int)ph1[i & 1], srcLane, 64);
                    apv.u[i] = (quad >= 2) ? u1 : u0;
                }
                ap[qh] = apv.v;
            }
            // ---- PV: o[qh][dc] += P @ V^T, V frag shared across qh ----
#pragma unroll
            for (int dc = 0; dc < 8; dc++) {
                int d = dc * 16 + cl;
                bf16x8 bv = *(const bf16x8*)&Vl[d * 32 + ((quad ^ (cl & 3)) * 8)];
                o[0][dc] = mfma16(ap[0], bv, o[0][dc]);
                o[1][dc] = mfma16(ap[1], bv, o[1][dc]);
            }
        }
        __syncthreads();   // drains stage vmcnt + LDS reads; flips buffers safely
        buf ^= 1;
    }
#undef STAGE

    // ---- epilogue: normalize (l lives at q=cl; o rows are q=quad*4+r) ----
#pragma unroll
    for (int qh = 0; qh < 2; qh++) {
        float linv[4];
#pragma unroll
        for (int r = 0; r < 4; r++)
            linv[r] = 1.f / __shfl(l_run[qh], quad * 4 + r, 64);
#pragma unroll
        for (int dc = 0; dc < 8; dc++) {
#pragma unroll
            for (int r = 0; r < 4; r++) {
                int row = qw0 + qh * 16 + quad * 4 + r;
                O[(size_t)row * HID + h * 128 + dc * 16 + cl] = f2b(o[qh][dc][r] * linv[r]);
            }
        }
    }
}

extern "C" void kernel_launch(void* const* d_in, const int* in_sizes, int n_in,
                              void* d_out, int out_size, void* d_ws, size_t ws_size,
                              hipStream_t stream) {
    const float* hs    = (const float*)d_in[0];
    const float* w_qkv = (const float*)d_in[1];
    const float* b_qkv = (const float*)d_in[2];
    const float* qw    = (const float*)d_in[3];
    const float* kw    = (const float*)d_in[4];
    const float* w_o   = (const float*)d_in[5];
    float* out = (float*)d_out;

    char* ws = (char*)d_ws;
    unsigned short* hsbf  = (unsigned short*)(ws);                 // 2048*4096*2  =  16777216
    unsigned short* wqkvT = (unsigned short*)(ws + 16777216);      // 12288*4096*2 = 100663296
    unsigned short* woT   = (unsigned short*)(ws + 117440512);     //  4096*4096*2 =  33554432
    float*          qkv   = (float*)(ws + 150994944);              //  2048*12288*4 = 100663296
    unsigned short* qbf   = (unsigned short*)(ws + 251658240);     //  16777216
    unsigned short* kbf   = (unsigned short*)(ws + 268435456);     //  16777216
    unsigned short* vT    = (unsigned short*)(ws + 285212672);     //  16777216
    unsigned short* attn  = (unsigned short*)(ws + 301989888);     //  16777216 (total ~318.8 MB)

    cast_f32_bf16<<<8192, 256, 0, stream>>>(hs, hsbf);
    transpose_f32_bf16<<<dim3(64, 192), 256, 0, stream>>>(w_qkv, wqkvT, HID, NQKV);
    transpose_f32_bf16<<<dim3(64, 64),  256, 0, stream>>>(w_o, woT, HID, HID);
    gemm_bt<1><<<dim3(16, 96), 256, 0, stream>>>(hsbf, wqkvT, b_qkv, qkv, NQKV, HID);
    rmsnorm_rope<<<T_SEQ, 256, 0, stream>>>(qkv, qw, kw, qbf, kbf);
    v_transpose<<<dim3(32, 32), 256, 0, stream>>>(qkv, vT);
    attn_kernel<<<dim3(32, 16), 256, 0, stream>>>(qbf, kbf, vT, attn);
    gemm_bt<0><<<dim3(16, 32), 256, 0, stream>>>(attn, woT, nullptr, out, HID, HID);
}